// Round 10
// baseline (1848.816 us; speedup 1.0000x reference)
//
#include <hip/hip_runtime.h>
#include <hip/hip_cooperative_groups.h>

namespace cg = cooperative_groups;

#define N_NODES 50000
#define N_EDGES 800000
#define N_GRAPHS 256
#define F 64
#define NBUCK 196          // ceil(50000/256) coarse buckets (dst>>8)
#define P3_TILE 2048
#define P3_GRID ((N_EDGES + P3_TILE - 1) / P3_TILE)
#define BCAP 6144
#define NB 768             // cooperative grid: 3 blocks/CU * 256 CU

// ---- bf16 helpers (RTN), all math stays f32 ----
__device__ __forceinline__ unsigned short f2bf(float f) {
    union { float f; unsigned u; } c; c.f = f;
    unsigned u = c.u + 0x7FFFu + ((c.u >> 16) & 1u);
    return (unsigned short)(u >> 16);
}
__device__ __forceinline__ float bfl(unsigned u) {
    union { unsigned u; float f; } c; c.u = u << 16; return c.f;
}
__device__ __forceinline__ float bfh(unsigned u) {
    union { unsigned u; float f; } c; c.u = u & 0xFFFF0000u; return c.f;
}

// ================= device phase functions (shared by mega + fallback) =================

// GEMM 64-row tile: Hn[i,:] = bf16((X[i,:] @ W) * dinv[i]); sm needs 33792 B
__device__ __forceinline__ void gemm_dev(const float* __restrict__ X,
                                         const float* __restrict__ W,
                                         const float* __restrict__ dinv,
                                         unsigned short* __restrict__ Hn,
                                         char* sm, int t, int bid, int nb) {
    float4* sW = (float4*)sm;            // 64*16 float4 = 16384 B
    float4* sX = sW + 64 * 16;           // 64*17 float4 = 17408 B
    const float4* W4 = (const float4*)W;
    const float4* X4 = (const float4*)X;
    int fg = t & 15, ng = t >> 4;
    for (int tile = bid; tile * 64 < N_NODES; tile += nb) {
        int base = tile * 64;
        for (int i = t; i < 64 * 16; i += 256) sW[i] = W4[i];
        for (int i = t; i < 64 * 16; i += 256) {
            int r = i >> 4, kg = i & 15;
            int node = base + r;
            sX[r * 17 + kg] = (node < N_NODES) ? X4[(size_t)node * 16 + kg]
                                               : make_float4(0.f, 0.f, 0.f, 0.f);
        }
        __syncthreads();
        float4 acc[4];
#pragma unroll
        for (int ii = 0; ii < 4; ii++) acc[ii] = make_float4(0.f, 0.f, 0.f, 0.f);
        for (int kg = 0; kg < 16; kg++) {
            float4 xv[4];
#pragma unroll
            for (int ii = 0; ii < 4; ii++) xv[ii] = sX[(ng + 16 * ii) * 17 + kg];
#pragma unroll
            for (int kk = 0; kk < 4; kk++) {
                float4 wv = sW[(4 * kg + kk) * 16 + fg];
#pragma unroll
                for (int ii = 0; ii < 4; ii++) {
                    float xs = (kk == 0) ? xv[ii].x : (kk == 1) ? xv[ii].y
                             : (kk == 2) ? xv[ii].z : xv[ii].w;
                    acc[ii].x += wv.x * xs; acc[ii].y += wv.y * xs;
                    acc[ii].z += wv.z * xs; acc[ii].w += wv.w * xs;
                }
            }
        }
        ushort4* H4 = (ushort4*)Hn;
#pragma unroll
        for (int ii = 0; ii < 4; ii++) {
            int node = base + ng + 16 * ii;
            if (node < N_NODES) {
                float d = dinv[node];
                float4 o = acc[ii];
                ushort4 u;
                u.x = f2bf(o.x * d); u.y = f2bf(o.y * d);
                u.z = f2bf(o.z * d); u.w = f2bf(o.w * d);
                H4[(size_t)node * 16 + fg] = u;
            }
        }
        __syncthreads();
    }
}

// gather: OUT[i,:] = relu(dinv[i]*(sum Hn[src] + Hn[i]) + b), wave-grid-stride
__device__ __forceinline__ void gather_dev(const int* __restrict__ rowptr,
                                           const int* __restrict__ eidx,
                                           const float* __restrict__ dinv,
                                           const unsigned short* __restrict__ Hn,
                                           const float* __restrict__ b,
                                           float* __restrict__ OUT,
                                           int t, int bid, int nb) {
    int lane = t & 63;
    int g = lane >> 3, f = lane & 7;
    const char* Hb = (const char*)Hn;
    int stride = nb * 4;
    for (int w = bid * 4 + (t >> 6); w < N_NODES; w += stride) {
        int beg = rowptr[w], end = rowptr[w + 1];
        float a0 = 0.f, a1 = 0.f, a2 = 0.f, a3 = 0.f;
        float a4 = 0.f, a5 = 0.f, a6 = 0.f, a7 = 0.f;
        int k = beg + g;
        for (; k + 8 < end; k += 16) {
            int o1 = eidx[k];
            int o2 = eidx[k + 8];
            uint4 p = *(const uint4*)(Hb + o1 + f * 16);
            uint4 q = *(const uint4*)(Hb + o2 + f * 16);
            a0 += bfl(p.x) + bfl(q.x); a1 += bfh(p.x) + bfh(q.x);
            a2 += bfl(p.y) + bfl(q.y); a3 += bfh(p.y) + bfh(q.y);
            a4 += bfl(p.z) + bfl(q.z); a5 += bfh(p.z) + bfh(q.z);
            a6 += bfl(p.w) + bfl(q.w); a7 += bfh(p.w) + bfh(q.w);
        }
        if (k < end) {
            int o1 = eidx[k];
            uint4 p = *(const uint4*)(Hb + o1 + f * 16);
            a0 += bfl(p.x); a1 += bfh(p.x);
            a2 += bfl(p.y); a3 += bfh(p.y);
            a4 += bfl(p.z); a5 += bfh(p.z);
            a6 += bfl(p.w); a7 += bfh(p.w);
        }
#pragma unroll
        for (int m = 8; m <= 32; m <<= 1) {
            a0 += __shfl_xor(a0, m); a1 += __shfl_xor(a1, m);
            a2 += __shfl_xor(a2, m); a3 += __shfl_xor(a3, m);
            a4 += __shfl_xor(a4, m); a5 += __shfl_xor(a5, m);
            a6 += __shfl_xor(a6, m); a7 += __shfl_xor(a7, m);
        }
        if (g == 0) {
            float di = dinv[w];
            uint4 hs = *(const uint4*)(Hb + (size_t)w * 128 + f * 16);
            float4 b0 = ((const float4*)b)[2 * f];
            float4 b1 = ((const float4*)b)[2 * f + 1];
            float4 o0, o1v;
            o0.x  = fmaxf(di * (a0 + bfl(hs.x)) + b0.x, 0.f);
            o0.y  = fmaxf(di * (a1 + bfh(hs.x)) + b0.y, 0.f);
            o0.z  = fmaxf(di * (a2 + bfl(hs.y)) + b0.z, 0.f);
            o0.w  = fmaxf(di * (a3 + bfh(hs.y)) + b0.w, 0.f);
            o1v.x = fmaxf(di * (a4 + bfl(hs.z)) + b1.x, 0.f);
            o1v.y = fmaxf(di * (a5 + bfh(hs.z)) + b1.y, 0.f);
            o1v.z = fmaxf(di * (a6 + bfl(hs.w)) + b1.z, 0.f);
            o1v.w = fmaxf(di * (a7 + bfh(hs.w)) + b1.w, 0.f);
            ((float4*)OUT)[(size_t)w * 16 + 2 * f]     = o0;
            ((float4*)OUT)[(size_t)w * 16 + 2 * f + 1] = o1v;
        }
    }
}

// ================= mega cooperative kernel =================
__global__ __launch_bounds__(256, 3) void mega(
    const float* __restrict__ x, const int* __restrict__ src,
    const int* __restrict__ dst, const int* __restrict__ batch,
    const float* __restrict__ W1, const float* __restrict__ b1,
    const float* __restrict__ W2, const float* __restrict__ b2,
    const float* __restrict__ W3, const float* __restrict__ b3,
    const float* __restrict__ Wl, const float* __restrict__ bl,
    float* __restrict__ out, unsigned short* __restrict__ Abf,
    float* __restrict__ B, float* __restrict__ dinv,
    int* __restrict__ rowptr, int* __restrict__ bcnt,
    int* __restrict__ bbase, int* __restrict__ bcur,
    unsigned int* __restrict__ bpair, int* __restrict__ eidx) {
    cg::grid_group grid = cg::this_grid();
    __shared__ float4 smem4[2112];   // 33792 B
    char* sm = (char*)smem4;
    const int t = threadIdx.x, bid = blockIdx.x, nb = gridDim.x;

    // P0: zero bucket counters
    for (int i = bid * 256 + t; i < NBUCK; i += nb * 256) bcnt[i] = 0;
    grid.sync();

    // P1: coarse histogram
    {
        int* h = (int*)sm;
        for (int i = t; i < NBUCK; i += 256) h[i] = 0;
        __syncthreads();
        for (int e = bid * 256 + t; e < N_EDGES; e += nb * 256)
            atomicAdd(&h[dst[e] >> 8], 1);
        __syncthreads();
        for (int i = t; i < NBUCK; i += 256)
            if (h[i]) atomicAdd(&bcnt[i], h[i]);
    }
    grid.sync();

    // P2: scan bucket counts (block 0)
    if (bid == 0) {
        int* s = (int*)sm;
        int v = (t < NBUCK) ? bcnt[t] : 0;
        s[t] = v;
        __syncthreads();
        for (int off = 1; off < 256; off <<= 1) {
            int u = (t >= off) ? s[t - off] : 0;
            __syncthreads();
            s[t] += u;
            __syncthreads();
        }
        int excl = s[t] - v;
        if (t < NBUCK) { bbase[t] = excl; bcur[t] = excl; }
        if (t == 255) bbase[NBUCK] = s[255];
    }
    grid.sync();

    // P3: partition edges into buckets
    for (int tile = bid; tile < P3_GRID; tile += nb) {
        int* bh = (int*)sm; int* bloc = bh + NBUCK; int* bpos = bloc + NBUCK;
        int lo = tile * P3_TILE, hi = min(lo + P3_TILE, N_EDGES);
        for (int i = t; i < NBUCK; i += 256) { bh[i] = 0; bpos[i] = 0; }
        __syncthreads();
        for (int e = lo + t; e < hi; e += 256) atomicAdd(&bh[dst[e] >> 8], 1);
        __syncthreads();
        for (int i = t; i < NBUCK; i += 256)
            bloc[i] = bh[i] ? atomicAdd(&bcur[i], bh[i]) : 0;
        __syncthreads();
        for (int e = lo + t; e < hi; e += 256) {
            int d = dst[e];
            int b = d >> 8;
            int r = atomicAdd(&bpos[b], 1);
            bpair[bloc[b] + r] = ((unsigned)src[e] << 8) | (unsigned)(d & 255);
        }
        __syncthreads();
    }
    grid.sync();

    // P4: per-bucket counting sort -> eidx (src*128), rowptr, dinv
    for (int b = bid; b < NBUCK; b += nb) {
        int* cnt = (int*)sm; int* s = cnt + 256; int* pos = s + 256;
        int* lout = pos + 256;
        int base = bbase[b], bend = bbase[b + 1], sz = bend - base;
        cnt[t] = 0;
        __syncthreads();
        for (int i = t; i < sz; i += 256) atomicAdd(&cnt[bpair[base + i] & 255], 1);
        __syncthreads();
        int v = cnt[t];
        s[t] = v;
        __syncthreads();
        for (int off = 1; off < 256; off <<= 1) {
            int u = (t >= off) ? s[t - off] : 0;
            __syncthreads();
            s[t] += u;
            __syncthreads();
        }
        int excl = s[t] - v;
        pos[t] = excl;
        int node = b * 256 + t;
        if (node < N_NODES) {
            rowptr[node] = base + excl;
            dinv[node] = 1.0f / sqrtf((float)v + 1.0f);
        }
        if (b == NBUCK - 1 && t == 0) rowptr[N_NODES] = bend;
        __syncthreads();
        if (sz <= BCAP) {
            for (int i = t; i < sz; i += 256) {
                unsigned p = bpair[base + i];
                int r = atomicAdd(&pos[p & 255], 1);
                lout[r] = (int)((p >> 8) << 7);
            }
            __syncthreads();
            for (int i = t; i < sz; i += 256) eidx[base + i] = lout[i];
        } else {
            for (int i = t; i < sz; i += 256) {
                unsigned p = bpair[base + i];
                int r = atomicAdd(&pos[p & 255], 1);
                eidx[base + r] = (int)((p >> 8) << 7);
            }
        }
        __syncthreads();
    }
    grid.sync();

    // layers
    gemm_dev(x, W1, dinv, Abf, sm, t, bid, nb);  grid.sync();
    gather_dev(rowptr, eidx, dinv, Abf, b1, B, t, bid, nb);  grid.sync();
    gemm_dev(B, W2, dinv, Abf, sm, t, bid, nb);  grid.sync();
    gather_dev(rowptr, eidx, dinv, Abf, b2, B, t, bid, nb);  grid.sync();
    gemm_dev(B, W3, dinv, Abf, sm, t, bid, nb);  grid.sync();
    gather_dev(rowptr, eidx, dinv, Abf, b3, B, t, bid, nb);  grid.sync();

    // pool + head: one block per graph
    for (int g = bid; g < N_GRAPHS; g += nb) {
        int* sint = (int*)sm;              // [0]=lo, [1]=hi
        float* sWl = (float*)(sint + 2);   // 64 floats
        float* wsum = sWl + 64;            // 4 floats
        if (t < 64) sWl[t] = Wl[t];
        if (t == 0) {
            int a = 0, bb = N_NODES;
            while (a < bb) { int m = (a + bb) >> 1; if (batch[m] < g) a = m + 1; else bb = m; }
            sint[0] = a;
            bb = N_NODES;
            while (a < bb) { int m = (a + bb) >> 1; if (batch[m] < g + 1) a = m + 1; else bb = m; }
            sint[1] = a;
        }
        __syncthreads();
        int lo = sint[0], hi = sint[1];
        int lane = t & 63, wave = t >> 6;
        float acc = 0.f;
        for (int node = lo + wave; node < hi; node += 4)
            acc += B[(size_t)node * 64 + lane] * sWl[lane];
#pragma unroll
        for (int off = 32; off > 0; off >>= 1) acc += __shfl_down(acc, off);
        if (lane == 0) wsum[wave] = acc;
        __syncthreads();
        if (t == 0) {
            float s = wsum[0] + wsum[1] + wsum[2] + wsum[3];
            float cntf = (float)(hi - lo);
            out[g] = s / fmaxf(cntf, 1.0f) + bl[0];
        }
        __syncthreads();
    }
}

// ================= fallback multi-kernel path (R9, proven) =================
__global__ __launch_bounds__(256) void fb_hist(const int* __restrict__ dst,
                                               int* __restrict__ bcnt) {
    __shared__ int h[NBUCK];
    int t = threadIdx.x;
    for (int i = t; i < NBUCK; i += 256) h[i] = 0;
    __syncthreads();
    for (int e = blockIdx.x * 256 + t; e < N_EDGES; e += gridDim.x * 256)
        atomicAdd(&h[dst[e] >> 8], 1);
    __syncthreads();
    for (int i = t; i < NBUCK; i += 256)
        if (h[i]) atomicAdd(&bcnt[i], h[i]);
}
__global__ __launch_bounds__(256) void fb_zero(int* __restrict__ bcnt) {
    int i = blockIdx.x * 256 + threadIdx.x;
    if (i < NBUCK) bcnt[i] = 0;
}
__global__ __launch_bounds__(256) void fb_scan(const int* __restrict__ bcnt,
                                               int* __restrict__ bbase,
                                               int* __restrict__ bcur) {
    __shared__ int s[256];
    int t = threadIdx.x;
    int v = (t < NBUCK) ? bcnt[t] : 0;
    s[t] = v;
    __syncthreads();
    for (int off = 1; off < 256; off <<= 1) {
        int u = (t >= off) ? s[t - off] : 0;
        __syncthreads();
        s[t] += u;
        __syncthreads();
    }
    int excl = s[t] - v;
    if (t < NBUCK) { bbase[t] = excl; bcur[t] = excl; }
    if (t == 255) bbase[NBUCK] = s[255];
}
__global__ __launch_bounds__(256) void fb_part(const int* __restrict__ src,
                                               const int* __restrict__ dst,
                                               int* __restrict__ bcur,
                                               unsigned int* __restrict__ bpair) {
    __shared__ int bh[NBUCK], bloc[NBUCK], bpos[NBUCK];
    int t = threadIdx.x;
    int lo = blockIdx.x * P3_TILE;
    int hi = min(lo + P3_TILE, N_EDGES);
    for (int i = t; i < NBUCK; i += 256) { bh[i] = 0; bpos[i] = 0; }
    __syncthreads();
    for (int e = lo + t; e < hi; e += 256) atomicAdd(&bh[dst[e] >> 8], 1);
    __syncthreads();
    for (int i = t; i < NBUCK; i += 256)
        bloc[i] = bh[i] ? atomicAdd(&bcur[i], bh[i]) : 0;
    __syncthreads();
    for (int e = lo + t; e < hi; e += 256) {
        int d = dst[e];
        int b = d >> 8;
        int r = atomicAdd(&bpos[b], 1);
        bpair[bloc[b] + r] = ((unsigned)src[e] << 8) | (unsigned)(d & 255);
    }
}
__global__ __launch_bounds__(256) void fb_sort(const unsigned int* __restrict__ bpair,
                                               const int* __restrict__ bbase,
                                               int* __restrict__ eidx,
                                               int* __restrict__ rowptr,
                                               float* __restrict__ dinv) {
    __shared__ int cnt[256], s[256], pos[256];
    __shared__ int lout[BCAP];
    int b = blockIdx.x, t = threadIdx.x;
    int base = bbase[b], bend = bbase[b + 1], sz = bend - base;
    cnt[t] = 0;
    __syncthreads();
    for (int i = t; i < sz; i += 256) atomicAdd(&cnt[bpair[base + i] & 255], 1);
    __syncthreads();
    int v = cnt[t];
    s[t] = v;
    __syncthreads();
    for (int off = 1; off < 256; off <<= 1) {
        int u = (t >= off) ? s[t - off] : 0;
        __syncthreads();
        s[t] += u;
        __syncthreads();
    }
    int excl = s[t] - v;
    pos[t] = excl;
    int node = b * 256 + t;
    if (node < N_NODES) {
        rowptr[node] = base + excl;
        dinv[node] = 1.0f / sqrtf((float)v + 1.0f);
    }
    if (b == NBUCK - 1 && t == 0) rowptr[N_NODES] = bend;
    __syncthreads();
    if (sz <= BCAP) {
        for (int i = t; i < sz; i += 256) {
            unsigned p = bpair[base + i];
            int r = atomicAdd(&pos[p & 255], 1);
            lout[r] = (int)((p >> 8) << 7);
        }
        __syncthreads();
        for (int i = t; i < sz; i += 256) eidx[base + i] = lout[i];
    } else {
        for (int i = t; i < sz; i += 256) {
            unsigned p = bpair[base + i];
            int r = atomicAdd(&pos[p & 255], 1);
            eidx[base + r] = (int)((p >> 8) << 7);
        }
    }
}
__global__ __launch_bounds__(256) void fb_gemm(const float* __restrict__ X,
                                               const float* __restrict__ W,
                                               const float* __restrict__ dinv,
                                               unsigned short* __restrict__ Hn) {
    __shared__ float4 smem4[2112];
    gemm_dev(X, W, dinv, Hn, (char*)smem4, threadIdx.x, blockIdx.x, gridDim.x);
}
__global__ __launch_bounds__(256) void fb_gather(const int* __restrict__ rowptr,
                                                 const int* __restrict__ eidx,
                                                 const float* __restrict__ dinv,
                                                 const unsigned short* __restrict__ Hn,
                                                 const float* __restrict__ b,
                                                 float* __restrict__ OUT) {
    gather_dev(rowptr, eidx, dinv, Hn, b, OUT, threadIdx.x, blockIdx.x, gridDim.x);
}
__global__ __launch_bounds__(256) void fb_pool(const float* __restrict__ H,
                                               const int* __restrict__ batch,
                                               const float* __restrict__ Wl,
                                               const float* __restrict__ bl,
                                               float* __restrict__ out) {
    int g = blockIdx.x;
    __shared__ int slo, shi;
    __shared__ float sWl[64];
    __shared__ float wsum[4];
    int tid = threadIdx.x;
    if (tid < 64) sWl[tid] = Wl[tid];
    if (tid == 0) {
        int a = 0, b = N_NODES;
        while (a < b) { int m = (a + b) >> 1; if (batch[m] < g) a = m + 1; else b = m; }
        slo = a;
        b = N_NODES;
        while (a < b) { int m = (a + b) >> 1; if (batch[m] < g + 1) a = m + 1; else b = m; }
        shi = a;
    }
    __syncthreads();
    int lo = slo, hi = shi;
    int lane = tid & 63, wave = tid >> 6;
    float acc = 0.f;
    for (int node = lo + wave; node < hi; node += 4)
        acc += H[(size_t)node * 64 + lane] * sWl[lane];
#pragma unroll
    for (int off = 32; off > 0; off >>= 1) acc += __shfl_down(acc, off);
    if (lane == 0) wsum[wave] = acc;
    __syncthreads();
    if (tid == 0) {
        float s = wsum[0] + wsum[1] + wsum[2] + wsum[3];
        float cnt = (float)(hi - lo);
        out[g] = s / fmaxf(cnt, 1.0f) + bl[0];
    }
}

extern "C" void kernel_launch(void* const* d_in, const int* in_sizes, int n_in,
                              void* d_out, int out_size, void* d_ws, size_t ws_size,
                              hipStream_t stream) {
    const float* x     = (const float*)d_in[0];
    const int*   src   = (const int*)d_in[1];
    const int*   dst   = (const int*)d_in[2];
    const int*   batch = (const int*)d_in[3];
    const float* W1 = (const float*)d_in[4];  const float* b1 = (const float*)d_in[5];
    const float* W2 = (const float*)d_in[6];  const float* b2 = (const float*)d_in[7];
    const float* W3 = (const float*)d_in[8];  const float* b3 = (const float*)d_in[9];
    const float* Wl = (const float*)d_in[10]; const float* bl = (const float*)d_in[11];
    float* out = (float*)d_out;

    char* ws = (char*)d_ws;
    unsigned short* Abf = (unsigned short*)ws;                   // N*F bf16
    float* B       = (float*)(ws + (size_t)N_NODES * F * 2);     // N*F f32
    float* dinv    = B + (size_t)N_NODES * F;                    // N
    int*   rowptr  = (int*)(dinv + N_NODES);                     // N+1
    int*   bcnt    = rowptr + N_NODES + 1;                       // NBUCK
    int*   bbase   = bcnt + NBUCK;                               // NBUCK+1
    int*   bcur    = bbase + NBUCK + 1;                          // NBUCK
    unsigned int* bpair = (unsigned int*)(bcur + NBUCK);         // E
    int*   eidx    = (int*)(bpair + N_EDGES);                    // E

    void* args[] = {
        (void*)&x, (void*)&src, (void*)&dst, (void*)&batch,
        (void*)&W1, (void*)&b1, (void*)&W2, (void*)&b2,
        (void*)&W3, (void*)&b3, (void*)&Wl, (void*)&bl,
        (void*)&out, (void*)&Abf, (void*)&B, (void*)&dinv,
        (void*)&rowptr, (void*)&bcnt, (void*)&bbase, (void*)&bcur,
        (void*)&bpair, (void*)&eidx
    };
    hipError_t err = hipLaunchCooperativeKernel((const void*)mega, dim3(NB), dim3(256),
                                                args, 0, stream);
    if (err != hipSuccess) {
        // fallback: proven multi-kernel path
        fb_zero<<<1, 256, 0, stream>>>(bcnt);
        fb_hist<<<256, 256, 0, stream>>>(dst, bcnt);
        fb_scan<<<1, 256, 0, stream>>>(bcnt, bbase, bcur);
        fb_part<<<P3_GRID, 256, 0, stream>>>(src, dst, bcur, bpair);
        fb_sort<<<NBUCK, 256, 0, stream>>>(bpair, bbase, eidx, rowptr, dinv);
        fb_gemm<<<782, 256, 0, stream>>>(x, W1, dinv, Abf);
        fb_gather<<<3125, 256, 0, stream>>>(rowptr, eidx, dinv, Abf, b1, B);
        fb_gemm<<<782, 256, 0, stream>>>(B, W2, dinv, Abf);
        fb_gather<<<3125, 256, 0, stream>>>(rowptr, eidx, dinv, Abf, b2, B);
        fb_gemm<<<782, 256, 0, stream>>>(B, W3, dinv, Abf);
        fb_gather<<<3125, 256, 0, stream>>>(rowptr, eidx, dinv, Abf, b3, B);
        fb_pool<<<N_GRAPHS, 256, 0, stream>>>(B, batch, Wl, bl, out);
    }
}

// Round 11
// 234.646 us; speedup vs baseline: 7.8792x; 7.8792x over previous
//
#include <hip/hip_runtime.h>

#define N_NODES 50000
#define N_EDGES 800000
#define N_GRAPHS 256
#define F 64
#define NBUCK 196          // ceil(50000/256) coarse buckets (dst>>8)
#define CAP 4608           // per-bucket capacity (mean 4082, sd ~64 -> 8 sigma)
#define P3_TILE 2048
#define P3_GRID ((N_EDGES + P3_TILE - 1) / P3_TILE)
#define BCAP 6144

// ---- bf16 helpers (RTN), all math stays f32 ----
__device__ __forceinline__ unsigned short f2bf(float f) {
    union { float f; unsigned u; } c; c.f = f;
    unsigned u = c.u + 0x7FFFu + ((c.u >> 16) & 1u);
    return (unsigned short)(u >> 16);
}
__device__ __forceinline__ float bfl(unsigned u) {
    union { unsigned u; float f; } c; c.u = u << 16; return c.f;
}
__device__ __forceinline__ float bfh(unsigned u) {
    union { unsigned u; float f; } c; c.u = u & 0xFFFF0000u; return c.f;
}

// ---------------- P1: partition edges into fixed-capacity buckets ----------------
__global__ __launch_bounds__(256) void partition_edges(const int* __restrict__ src,
                                                       const int* __restrict__ dst,
                                                       int* __restrict__ bcur,
                                                       unsigned int* __restrict__ bpair) {
    __shared__ int bh[NBUCK], bloc[NBUCK], bpos[NBUCK];
    int t = threadIdx.x;
    int lo = blockIdx.x * P3_TILE;
    int hi = min(lo + P3_TILE, N_EDGES);
    for (int i = t; i < NBUCK; i += 256) { bh[i] = 0; bpos[i] = 0; }
    __syncthreads();
    for (int e = lo + t; e < hi; e += 256) atomicAdd(&bh[dst[e] >> 8], 1);
    __syncthreads();
    for (int i = t; i < NBUCK; i += 256)
        bloc[i] = bh[i] ? atomicAdd(&bcur[i], bh[i]) : 0;
    __syncthreads();
    for (int e = lo + t; e < hi; e += 256) {
        int d = dst[e];
        int b = d >> 8;
        int r = atomicAdd(&bpos[b], 1);
        bpair[(size_t)b * CAP + bloc[b] + r] = ((unsigned)src[e] << 8) | (unsigned)(d & 255);
    }
}

// ---------------- P2: per-bucket LDS counting sort -> eidx (src*128), rbeg/rend, dinv ----------------
__global__ __launch_bounds__(256) void bucket_sort(const unsigned int* __restrict__ bpair,
                                                   const int* __restrict__ bcur,
                                                   int* __restrict__ eidx,
                                                   int* __restrict__ rbeg,
                                                   int* __restrict__ rend,
                                                   float* __restrict__ dinv) {
    __shared__ int cnt[256], s[256], pos[256];
    __shared__ int lout[BCAP];
    int b = blockIdx.x, t = threadIdx.x;
    int base = b * CAP;
    int sz = bcur[b];

    cnt[t] = 0;
    __syncthreads();
    for (int i = t; i < sz; i += 256) atomicAdd(&cnt[bpair[base + i] & 255], 1);
    __syncthreads();
    int v = cnt[t];
    s[t] = v;
    __syncthreads();
    for (int off = 1; off < 256; off <<= 1) {
        int u = (t >= off) ? s[t - off] : 0;
        __syncthreads();
        s[t] += u;
        __syncthreads();
    }
    int excl = s[t] - v;
    pos[t] = excl;
    int node = b * 256 + t;
    if (node < N_NODES) {
        rbeg[node] = base + excl;
        rend[node] = base + excl + v;
        dinv[node] = 1.0f / sqrtf((float)v + 1.0f);   // +1 self-loop
    }
    __syncthreads();

    if (sz <= BCAP) {
        for (int i = t; i < sz; i += 256) {
            unsigned p = bpair[base + i];
            int r = atomicAdd(&pos[p & 255], 1);
            lout[r] = (int)((p >> 8) << 7);   // src byte offset (src*128, bf16 row)
        }
        __syncthreads();
        for (int i = t; i < sz; i += 256) eidx[base + i] = lout[i];
    } else {
        for (int i = t; i < sz; i += 256) {
            unsigned p = bpair[base + i];
            int r = atomicAdd(&pos[p & 255], 1);
            eidx[base + r] = (int)((p >> 8) << 7);
        }
    }
}

// ---------------- GEMM + dinv fold: Hn[i,:] = bf16( (X[i,:] @ W) * dinv[i] ) ----------------
#define XSTRIDE 17
__global__ __launch_bounds__(256) void gemm64_v(const float* __restrict__ X,
                                                const float* __restrict__ W,
                                                const float* __restrict__ dinv,
                                                unsigned short* __restrict__ Hn, int n) {
    __shared__ float4 sW[64 * 16];
    __shared__ float4 sX[128 * XSTRIDE];
    int tid = threadIdx.x;
    int base = blockIdx.x * 128;

    const float4* W4 = (const float4*)W;
    for (int i = tid; i < 64 * 16; i += 256) sW[i] = W4[i];
    const float4* X4 = (const float4*)X;
    for (int i = tid; i < 128 * 16; i += 256) {
        int r = i >> 4, kg = i & 15;
        int node = base + r;
        sX[r * XSTRIDE + kg] = (node < n) ? X4[(size_t)node * 16 + kg]
                                          : make_float4(0.f, 0.f, 0.f, 0.f);
    }
    __syncthreads();

    int fg = tid & 15;
    int ng = tid >> 4;
    float4 acc[8];
#pragma unroll
    for (int ii = 0; ii < 8; ii++) acc[ii] = make_float4(0.f, 0.f, 0.f, 0.f);

    for (int kg = 0; kg < 16; kg++) {
        float4 xv[8];
#pragma unroll
        for (int ii = 0; ii < 8; ii++) xv[ii] = sX[(ng + 16 * ii) * XSTRIDE + kg];
#pragma unroll
        for (int kk = 0; kk < 4; kk++) {
            float4 wv = sW[(4 * kg + kk) * 16 + fg];
#pragma unroll
            for (int ii = 0; ii < 8; ii++) {
                float xs = (kk == 0) ? xv[ii].x : (kk == 1) ? xv[ii].y
                         : (kk == 2) ? xv[ii].z : xv[ii].w;
                acc[ii].x += wv.x * xs;
                acc[ii].y += wv.y * xs;
                acc[ii].z += wv.z * xs;
                acc[ii].w += wv.w * xs;
            }
        }
    }

    ushort4* H4 = (ushort4*)Hn;
#pragma unroll
    for (int ii = 0; ii < 8; ii++) {
        int node = base + ng + 16 * ii;
        if (node < n) {
            float d = dinv[node];
            float4 o = acc[ii];
            ushort4 u;
            u.x = f2bf(o.x * d); u.y = f2bf(o.y * d);
            u.z = f2bf(o.z * d); u.w = f2bf(o.w * d);
            H4[(size_t)node * 16 + fg] = u;
        }
    }
}

// ---------------- fused gather + epilogue (layers 1,2) ----------------
__global__ __launch_bounds__(256) void gather_layer(const int* __restrict__ rbeg,
                                                    const int* __restrict__ rend,
                                                    const int* __restrict__ eidx,
                                                    const float* __restrict__ dinv,
                                                    const unsigned short* __restrict__ Hn,
                                                    const float* __restrict__ b,
                                                    float* __restrict__ OUT, int n) {
    int w = (blockIdx.x * blockDim.x + threadIdx.x) >> 6;
    int lane = threadIdx.x & 63;
    if (w >= n) return;
    int g = lane >> 3;
    int f = lane & 7;
    int beg = rbeg[w], end = rend[w];
    const char* Hb = (const char*)Hn;

    float a0 = 0.f, a1 = 0.f, a2 = 0.f, a3 = 0.f;
    float a4 = 0.f, a5 = 0.f, a6 = 0.f, a7 = 0.f;
    int k = beg + g;
    for (; k + 8 < end; k += 16) {
        int o1 = eidx[k];
        int o2 = eidx[k + 8];
        uint4 p = *(const uint4*)(Hb + o1 + f * 16);
        uint4 q = *(const uint4*)(Hb + o2 + f * 16);
        a0 += bfl(p.x) + bfl(q.x); a1 += bfh(p.x) + bfh(q.x);
        a2 += bfl(p.y) + bfl(q.y); a3 += bfh(p.y) + bfh(q.y);
        a4 += bfl(p.z) + bfl(q.z); a5 += bfh(p.z) + bfh(q.z);
        a6 += bfl(p.w) + bfl(q.w); a7 += bfh(p.w) + bfh(q.w);
    }
    if (k < end) {
        int o1 = eidx[k];
        uint4 p = *(const uint4*)(Hb + o1 + f * 16);
        a0 += bfl(p.x); a1 += bfh(p.x);
        a2 += bfl(p.y); a3 += bfh(p.y);
        a4 += bfl(p.z); a5 += bfh(p.z);
        a6 += bfl(p.w); a7 += bfh(p.w);
    }
#pragma unroll
    for (int m = 8; m <= 32; m <<= 1) {
        a0 += __shfl_xor(a0, m); a1 += __shfl_xor(a1, m);
        a2 += __shfl_xor(a2, m); a3 += __shfl_xor(a3, m);
        a4 += __shfl_xor(a4, m); a5 += __shfl_xor(a5, m);
        a6 += __shfl_xor(a6, m); a7 += __shfl_xor(a7, m);
    }

    if (g == 0) {
        float di = dinv[w];
        uint4 hs = *(const uint4*)(Hb + (size_t)w * 128 + f * 16);
        float4 b0 = ((const float4*)b)[2 * f];
        float4 b1 = ((const float4*)b)[2 * f + 1];
        float4 o0, o1v;
        o0.x  = fmaxf(di * (a0 + bfl(hs.x)) + b0.x, 0.f);
        o0.y  = fmaxf(di * (a1 + bfh(hs.x)) + b0.y, 0.f);
        o0.z  = fmaxf(di * (a2 + bfl(hs.y)) + b0.z, 0.f);
        o0.w  = fmaxf(di * (a3 + bfh(hs.y)) + b0.w, 0.f);
        o1v.x = fmaxf(di * (a4 + bfl(hs.z)) + b1.x, 0.f);
        o1v.y = fmaxf(di * (a5 + bfh(hs.z)) + b1.y, 0.f);
        o1v.z = fmaxf(di * (a6 + bfl(hs.w)) + b1.z, 0.f);
        o1v.w = fmaxf(di * (a7 + bfh(hs.w)) + b1.w, 0.f);
        ((float4*)OUT)[(size_t)w * 16 + 2 * f]     = o0;
        ((float4*)OUT)[(size_t)w * 16 + 2 * f + 1] = o1v;
    }
}

// ---------------- layer-3 gather fused with pooling dot: writes pdot[node] only ----------------
__global__ __launch_bounds__(256) void gather_pool(const int* __restrict__ rbeg,
                                                   const int* __restrict__ rend,
                                                   const int* __restrict__ eidx,
                                                   const float* __restrict__ dinv,
                                                   const unsigned short* __restrict__ Hn,
                                                   const float* __restrict__ b,
                                                   const float* __restrict__ Wl,
                                                   float* __restrict__ pdot, int n) {
    int w = (blockIdx.x * blockDim.x + threadIdx.x) >> 6;
    int lane = threadIdx.x & 63;
    if (w >= n) return;
    int g = lane >> 3;
    int f = lane & 7;
    int beg = rbeg[w], end = rend[w];
    const char* Hb = (const char*)Hn;

    float a0 = 0.f, a1 = 0.f, a2 = 0.f, a3 = 0.f;
    float a4 = 0.f, a5 = 0.f, a6 = 0.f, a7 = 0.f;
    int k = beg + g;
    for (; k + 8 < end; k += 16) {
        int o1 = eidx[k];
        int o2 = eidx[k + 8];
        uint4 p = *(const uint4*)(Hb + o1 + f * 16);
        uint4 q = *(const uint4*)(Hb + o2 + f * 16);
        a0 += bfl(p.x) + bfl(q.x); a1 += bfh(p.x) + bfh(q.x);
        a2 += bfl(p.y) + bfl(q.y); a3 += bfh(p.y) + bfh(q.y);
        a4 += bfl(p.z) + bfl(q.z); a5 += bfh(p.z) + bfh(q.z);
        a6 += bfl(p.w) + bfl(q.w); a7 += bfh(p.w) + bfh(q.w);
    }
    if (k < end) {
        int o1 = eidx[k];
        uint4 p = *(const uint4*)(Hb + o1 + f * 16);
        a0 += bfl(p.x); a1 += bfh(p.x);
        a2 += bfl(p.y); a3 += bfh(p.y);
        a4 += bfl(p.z); a5 += bfh(p.z);
        a6 += bfl(p.w); a7 += bfh(p.w);
    }
#pragma unroll
    for (int m = 8; m <= 32; m <<= 1) {
        a0 += __shfl_xor(a0, m); a1 += __shfl_xor(a1, m);
        a2 += __shfl_xor(a2, m); a3 += __shfl_xor(a3, m);
        a4 += __shfl_xor(a4, m); a5 += __shfl_xor(a5, m);
        a6 += __shfl_xor(a6, m); a7 += __shfl_xor(a7, m);
    }

    // all lanes hold full sums for their feature octet f; compute relu'd
    // features and partial dot with Wl, then reduce across f (masks 1,2,4).
    float di = dinv[w];
    uint4 hs = *(const uint4*)(Hb + (size_t)w * 128 + f * 16);
    float4 b0 = ((const float4*)b)[2 * f];
    float4 b1 = ((const float4*)b)[2 * f + 1];
    float4 w0 = ((const float4*)Wl)[2 * f];
    float4 w1 = ((const float4*)Wl)[2 * f + 1];
    float d = 0.f;
    d += fmaxf(di * (a0 + bfl(hs.x)) + b0.x, 0.f) * w0.x;
    d += fmaxf(di * (a1 + bfh(hs.x)) + b0.y, 0.f) * w0.y;
    d += fmaxf(di * (a2 + bfl(hs.y)) + b0.z, 0.f) * w0.z;
    d += fmaxf(di * (a3 + bfh(hs.y)) + b0.w, 0.f) * w0.w;
    d += fmaxf(di * (a4 + bfl(hs.z)) + b1.x, 0.f) * w1.x;
    d += fmaxf(di * (a5 + bfh(hs.z)) + b1.y, 0.f) * w1.y;
    d += fmaxf(di * (a6 + bfl(hs.w)) + b1.z, 0.f) * w1.z;
    d += fmaxf(di * (a7 + bfh(hs.w)) + b1.w, 0.f) * w1.w;
#pragma unroll
    for (int m = 1; m <= 4; m <<= 1) d += __shfl_xor(d, m);
    if (lane == 0) pdot[w] = d;
}

// ---------------- final: per-graph mean of pdot + bias ----------------
__global__ __launch_bounds__(64) void final_out(const float* __restrict__ pdot,
                                                const int* __restrict__ batch,
                                                const float* __restrict__ bl,
                                                float* __restrict__ out) {
    int g = blockIdx.x;
    __shared__ int slo, shi;
    int lane = threadIdx.x;
    if (lane == 0) {
        int a = 0, b = N_NODES;
        while (a < b) { int m = (a + b) >> 1; if (batch[m] < g) a = m + 1; else b = m; }
        slo = a;
        b = N_NODES;
        while (a < b) { int m = (a + b) >> 1; if (batch[m] < g + 1) a = m + 1; else b = m; }
        shi = a;
    }
    __syncthreads();
    int lo = slo, hi = shi;
    float acc = 0.f;
    for (int i = lo + lane; i < hi; i += 64) acc += pdot[i];
#pragma unroll
    for (int off = 32; off > 0; off >>= 1) acc += __shfl_down(acc, off);
    if (lane == 0) {
        float cnt = (float)(hi - lo);
        out[g] = acc / fmaxf(cnt, 1.0f) + bl[0];
    }
}

extern "C" void kernel_launch(void* const* d_in, const int* in_sizes, int n_in,
                              void* d_out, int out_size, void* d_ws, size_t ws_size,
                              hipStream_t stream) {
    const float* x     = (const float*)d_in[0];
    const int*   src   = (const int*)d_in[1];
    const int*   dst   = (const int*)d_in[2];
    const int*   batch = (const int*)d_in[3];
    const float* W1 = (const float*)d_in[4];  const float* b1 = (const float*)d_in[5];
    const float* W2 = (const float*)d_in[6];  const float* b2 = (const float*)d_in[7];
    const float* W3 = (const float*)d_in[8];  const float* b3 = (const float*)d_in[9];
    const float* Wl = (const float*)d_in[10]; const float* bl = (const float*)d_in[11];
    float* out = (float*)d_out;

    char* ws = (char*)d_ws;
    unsigned short* Abf = (unsigned short*)ws;                   // N*F bf16 (Hn)
    float* B       = (float*)(ws + (size_t)N_NODES * F * 2);     // N*F f32 (H)
    float* dinv    = B + (size_t)N_NODES * F;                    // N
    float* pdot    = dinv + N_NODES;                             // N
    int*   rbeg    = (int*)(pdot + N_NODES);                     // N
    int*   rend    = rbeg + N_NODES;                             // N
    int*   bcur    = rend + N_NODES;                             // NBUCK
    unsigned int* bpair = (unsigned int*)(bcur + NBUCK);         // NBUCK*CAP
    int*   eidx    = (int*)(bpair + (size_t)NBUCK * CAP);        // NBUCK*CAP

    const int GEMM_GRID     = (N_NODES + 127) / 128;             // 391
    const int NODEWAVE_GRID = (N_NODES * 64 + 255) / 256;        // 12500

    // ---- preprocessing: padded-CSR build (rbeg/rend, eidx, dinv) ----
    hipMemsetAsync(bcur, 0, NBUCK * sizeof(int), stream);
    partition_edges<<<P3_GRID, 256, 0, stream>>>(src, dst, bcur, bpair);
    bucket_sort<<<NBUCK, 256, 0, stream>>>(bpair, bcur, eidx, rbeg, rend, dinv);

    // ---- layer 1 ----
    gemm64_v<<<GEMM_GRID, 256, 0, stream>>>(x, W1, dinv, Abf, N_NODES);
    gather_layer<<<NODEWAVE_GRID, 256, 0, stream>>>(rbeg, rend, eidx, dinv, Abf, b1, B, N_NODES);

    // ---- layer 2 ----
    gemm64_v<<<GEMM_GRID, 256, 0, stream>>>(B, W2, dinv, Abf, N_NODES);
    gather_layer<<<NODEWAVE_GRID, 256, 0, stream>>>(rbeg, rend, eidx, dinv, Abf, b2, B, N_NODES);

    // ---- layer 3: gather fused with pooling dot ----
    gemm64_v<<<GEMM_GRID, 256, 0, stream>>>(B, W3, dinv, Abf, N_NODES);
    gather_pool<<<NODEWAVE_GRID, 256, 0, stream>>>(rbeg, rend, eidx, dinv, Abf, b3, Wl, pdot, N_NODES);

    // ---- final: per-graph mean + bias ----
    final_out<<<N_GRAPHS, 64, 0, stream>>>(pdot, batch, bl, out);
}

// Round 12
// 221.920 us; speedup vs baseline: 8.3310x; 1.0573x over previous
//
#include <hip/hip_runtime.h>

#define N_NODES 50000
#define N_EDGES 800000
#define N_GRAPHS 256
#define F 64
#define NBUCK 196          // ceil(50000/256) coarse buckets (dst>>8)
#define CAP 4608           // per-bucket capacity (mean 4082, sd ~64 -> 8 sigma)
#define P3_TILE 2048
#define P3_GRID ((N_EDGES + P3_TILE - 1) / P3_TILE)
#define BCAP 6144

// ---- bf16 helpers (RTN), all math stays f32 ----
__device__ __forceinline__ unsigned short f2bf(float f) {
    union { float f; unsigned u; } c; c.f = f;
    unsigned u = c.u + 0x7FFFu + ((c.u >> 16) & 1u);
    return (unsigned short)(u >> 16);
}
__device__ __forceinline__ unsigned pack2bf(float lo, float hi) {
    return (unsigned)f2bf(lo) | ((unsigned)f2bf(hi) << 16);
}
__device__ __forceinline__ float bfl(unsigned u) {
    union { unsigned u; float f; } c; c.u = u << 16; return c.f;
}
__device__ __forceinline__ float bfh(unsigned u) {
    union { unsigned u; float f; } c; c.u = u & 0xFFFF0000u; return c.f;
}

// ---------------- P1: partition edges into fixed-capacity buckets ----------------
__global__ __launch_bounds__(256) void partition_edges(const int* __restrict__ src,
                                                       const int* __restrict__ dst,
                                                       int* __restrict__ bcur,
                                                       unsigned int* __restrict__ bpair) {
    __shared__ int bh[NBUCK], bloc[NBUCK], bpos[NBUCK];
    int t = threadIdx.x;
    int lo = blockIdx.x * P3_TILE;
    int hi = min(lo + P3_TILE, N_EDGES);
    for (int i = t; i < NBUCK; i += 256) { bh[i] = 0; bpos[i] = 0; }
    __syncthreads();
    for (int e = lo + t; e < hi; e += 256) atomicAdd(&bh[dst[e] >> 8], 1);
    __syncthreads();
    for (int i = t; i < NBUCK; i += 256)
        bloc[i] = bh[i] ? atomicAdd(&bcur[i], bh[i]) : 0;
    __syncthreads();
    for (int e = lo + t; e < hi; e += 256) {
        int d = dst[e];
        int b = d >> 8;
        int r = atomicAdd(&bpos[b], 1);
        bpair[(size_t)b * CAP + bloc[b] + r] = ((unsigned)src[e] << 8) | (unsigned)(d & 255);
    }
}

// ---------------- P2: per-bucket LDS counting sort -> eidx (src*128), rbeg/rend, dinv ----------------
__global__ __launch_bounds__(256) void bucket_sort(const unsigned int* __restrict__ bpair,
                                                   const int* __restrict__ bcur,
                                                   int* __restrict__ eidx,
                                                   int* __restrict__ rbeg,
                                                   int* __restrict__ rend,
                                                   float* __restrict__ dinv) {
    __shared__ int cnt[256], s[256], pos[256];
    __shared__ int lout[BCAP];
    int b = blockIdx.x, t = threadIdx.x;
    int base = b * CAP;
    int sz = bcur[b];

    cnt[t] = 0;
    __syncthreads();
    for (int i = t; i < sz; i += 256) atomicAdd(&cnt[bpair[base + i] & 255], 1);
    __syncthreads();
    int v = cnt[t];
    s[t] = v;
    __syncthreads();
    for (int off = 1; off < 256; off <<= 1) {
        int u = (t >= off) ? s[t - off] : 0;
        __syncthreads();
        s[t] += u;
        __syncthreads();
    }
    int excl = s[t] - v;
    pos[t] = excl;
    int node = b * 256 + t;
    if (node < N_NODES) {
        rbeg[node] = base + excl;
        rend[node] = base + excl + v;
        dinv[node] = 1.0f / sqrtf((float)v + 1.0f);   // +1 self-loop
    }
    __syncthreads();

    if (sz <= BCAP) {
        for (int i = t; i < sz; i += 256) {
            unsigned p = bpair[base + i];
            int r = atomicAdd(&pos[p & 255], 1);
            lout[r] = (int)((p >> 8) << 7);   // src byte offset (src*128, bf16 row)
        }
        __syncthreads();
        for (int i = t; i < sz; i += 256) eidx[base + i] = lout[i];
    } else {
        for (int i = t; i < sz; i += 256) {
            unsigned p = bpair[base + i];
            int r = atomicAdd(&pos[p & 255], 1);
            eidx[base + r] = (int)((p >> 8) << 7);
        }
    }
}

// ---------------- GEMM + dinv fold: Hn[i,:] = bf16( (X[i,:] @ W) * dinv[i] ) ----------------
// BF16IN=false: X is f32 (layer 1). BF16IN=true: X is bf16 rows (layers 2,3).
#define XSTRIDE 17
template <bool BF16IN>
__global__ __launch_bounds__(256) void gemm64_t(const void* __restrict__ Xv,
                                                const float* __restrict__ W,
                                                const float* __restrict__ dinv,
                                                unsigned short* __restrict__ Hn, int n) {
    __shared__ float4 sW[64 * 16];
    __shared__ float4 sX[128 * XSTRIDE];
    int tid = threadIdx.x;
    int base = blockIdx.x * 128;

    const float4* W4 = (const float4*)W;
    for (int i = tid; i < 64 * 16; i += 256) sW[i] = W4[i];
    if (BF16IN) {
        const uint4* X4 = (const uint4*)Xv;    // row = 8 uint4 (64 bf16)
        for (int i = tid; i < 128 * 8; i += 256) {
            int r = i >> 3, c = i & 7;
            int node = base + r;
            uint4 u = (node < n) ? X4[(size_t)node * 8 + c]
                                 : make_uint4(0u, 0u, 0u, 0u);
            sX[r * XSTRIDE + 2 * c]     = make_float4(bfl(u.x), bfh(u.x), bfl(u.y), bfh(u.y));
            sX[r * XSTRIDE + 2 * c + 1] = make_float4(bfl(u.z), bfh(u.z), bfl(u.w), bfh(u.w));
        }
    } else {
        const float4* X4 = (const float4*)Xv;
        for (int i = tid; i < 128 * 16; i += 256) {
            int r = i >> 4, kg = i & 15;
            int node = base + r;
            sX[r * XSTRIDE + kg] = (node < n) ? X4[(size_t)node * 16 + kg]
                                              : make_float4(0.f, 0.f, 0.f, 0.f);
        }
    }
    __syncthreads();

    int fg = tid & 15;
    int ng = tid >> 4;
    float4 acc[8];
#pragma unroll
    for (int ii = 0; ii < 8; ii++) acc[ii] = make_float4(0.f, 0.f, 0.f, 0.f);

    for (int kg = 0; kg < 16; kg++) {
        float4 xv[8];
#pragma unroll
        for (int ii = 0; ii < 8; ii++) xv[ii] = sX[(ng + 16 * ii) * XSTRIDE + kg];
#pragma unroll
        for (int kk = 0; kk < 4; kk++) {
            float4 wv = sW[(4 * kg + kk) * 16 + fg];
#pragma unroll
            for (int ii = 0; ii < 8; ii++) {
                float xs = (kk == 0) ? xv[ii].x : (kk == 1) ? xv[ii].y
                         : (kk == 2) ? xv[ii].z : xv[ii].w;
                acc[ii].x += wv.x * xs;
                acc[ii].y += wv.y * xs;
                acc[ii].z += wv.z * xs;
                acc[ii].w += wv.w * xs;
            }
        }
    }

    ushort4* H4 = (ushort4*)Hn;
#pragma unroll
    for (int ii = 0; ii < 8; ii++) {
        int node = base + ng + 16 * ii;
        if (node < n) {
            float d = dinv[node];
            float4 o = acc[ii];
            ushort4 u;
            u.x = f2bf(o.x * d); u.y = f2bf(o.y * d);
            u.z = f2bf(o.z * d); u.w = f2bf(o.w * d);
            H4[(size_t)node * 16 + fg] = u;
        }
    }
}

// ---------------- gather (layers 1,2): 8 nodes/wave, no cross-subgroup reduce ----------------
// lane = ns*8+f: node = wave*8+ns, feature octet f (features 8f..8f+8).
// OUT is bf16 rows (128 B/node).
__global__ __launch_bounds__(256) void gather_layer(const int* __restrict__ rbeg,
                                                    const int* __restrict__ rend,
                                                    const int* __restrict__ eidx,
                                                    const float* __restrict__ dinv,
                                                    const unsigned short* __restrict__ Hn,
                                                    const float* __restrict__ b,
                                                    unsigned short* __restrict__ OUT, int n) {
    int wv = (blockIdx.x * blockDim.x + threadIdx.x) >> 6;
    int lane = threadIdx.x & 63;
    int ns = lane >> 3, f = lane & 7;
    int node = wv * 8 + ns;
    bool valid = node < n;
    int beg = valid ? rbeg[node] : 0;
    int end = valid ? rend[node] : 0;
    const char* Hb = (const char*)Hn;

    float a0 = 0.f, a1 = 0.f, a2 = 0.f, a3 = 0.f;
    float a4 = 0.f, a5 = 0.f, a6 = 0.f, a7 = 0.f;
    int k = beg;
    for (; k + 1 < end; k += 2) {
        int o1 = eidx[k];
        int o2 = eidx[k + 1];
        uint4 p = *(const uint4*)(Hb + o1 + f * 16);
        uint4 q = *(const uint4*)(Hb + o2 + f * 16);
        a0 += bfl(p.x) + bfl(q.x); a1 += bfh(p.x) + bfh(q.x);
        a2 += bfl(p.y) + bfl(q.y); a3 += bfh(p.y) + bfh(q.y);
        a4 += bfl(p.z) + bfl(q.z); a5 += bfh(p.z) + bfh(q.z);
        a6 += bfl(p.w) + bfl(q.w); a7 += bfh(p.w) + bfh(q.w);
    }
    if (k < end) {
        int o1 = eidx[k];
        uint4 p = *(const uint4*)(Hb + o1 + f * 16);
        a0 += bfl(p.x); a1 += bfh(p.x);
        a2 += bfl(p.y); a3 += bfh(p.y);
        a4 += bfl(p.z); a5 += bfh(p.z);
        a6 += bfl(p.w); a7 += bfh(p.w);
    }

    if (valid) {
        float di = dinv[node];
        uint4 hs = *(const uint4*)(Hb + (size_t)node * 128 + f * 16);
        float4 b0 = ((const float4*)b)[2 * f];
        float4 b1 = ((const float4*)b)[2 * f + 1];
        float v0 = fmaxf(di * (a0 + bfl(hs.x)) + b0.x, 0.f);
        float v1 = fmaxf(di * (a1 + bfh(hs.x)) + b0.y, 0.f);
        float v2 = fmaxf(di * (a2 + bfl(hs.y)) + b0.z, 0.f);
        float v3 = fmaxf(di * (a3 + bfh(hs.y)) + b0.w, 0.f);
        float v4 = fmaxf(di * (a4 + bfl(hs.z)) + b1.x, 0.f);
        float v5 = fmaxf(di * (a5 + bfh(hs.z)) + b1.y, 0.f);
        float v6 = fmaxf(di * (a6 + bfl(hs.w)) + b1.z, 0.f);
        float v7 = fmaxf(di * (a7 + bfh(hs.w)) + b1.w, 0.f);
        uint4 u;
        u.x = pack2bf(v0, v1); u.y = pack2bf(v2, v3);
        u.z = pack2bf(v4, v5); u.w = pack2bf(v6, v7);
        ((uint4*)OUT)[(size_t)node * 8 + f] = u;
    }
}

// ---------------- layer-3 gather fused with pooling dot: writes pdot[node] ----------------
__global__ __launch_bounds__(256) void gather_pool(const int* __restrict__ rbeg,
                                                   const int* __restrict__ rend,
                                                   const int* __restrict__ eidx,
                                                   const float* __restrict__ dinv,
                                                   const unsigned short* __restrict__ Hn,
                                                   const float* __restrict__ b,
                                                   const float* __restrict__ Wl,
                                                   float* __restrict__ pdot, int n) {
    int wv = (blockIdx.x * blockDim.x + threadIdx.x) >> 6;
    int lane = threadIdx.x & 63;
    int ns = lane >> 3, f = lane & 7;
    int node = wv * 8 + ns;
    bool valid = node < n;
    int beg = valid ? rbeg[node] : 0;
    int end = valid ? rend[node] : 0;
    const char* Hb = (const char*)Hn;

    float a0 = 0.f, a1 = 0.f, a2 = 0.f, a3 = 0.f;
    float a4 = 0.f, a5 = 0.f, a6 = 0.f, a7 = 0.f;
    int k = beg;
    for (; k + 1 < end; k += 2) {
        int o1 = eidx[k];
        int o2 = eidx[k + 1];
        uint4 p = *(const uint4*)(Hb + o1 + f * 16);
        uint4 q = *(const uint4*)(Hb + o2 + f * 16);
        a0 += bfl(p.x) + bfl(q.x); a1 += bfh(p.x) + bfh(q.x);
        a2 += bfl(p.y) + bfl(q.y); a3 += bfh(p.y) + bfh(q.y);
        a4 += bfl(p.z) + bfl(q.z); a5 += bfh(p.z) + bfh(q.z);
        a6 += bfl(p.w) + bfl(q.w); a7 += bfh(p.w) + bfh(q.w);
    }
    if (k < end) {
        int o1 = eidx[k];
        uint4 p = *(const uint4*)(Hb + o1 + f * 16);
        a0 += bfl(p.x); a1 += bfh(p.x);
        a2 += bfl(p.y); a3 += bfh(p.y);
        a4 += bfl(p.z); a5 += bfh(p.z);
        a6 += bfl(p.w); a7 += bfh(p.w);
    }

    float di = valid ? dinv[node] : 0.f;
    uint4 hs = valid ? *(const uint4*)(Hb + (size_t)node * 128 + f * 16)
                     : make_uint4(0u, 0u, 0u, 0u);
    float4 b0 = ((const float4*)b)[2 * f];
    float4 b1 = ((const float4*)b)[2 * f + 1];
    float4 w0 = ((const float4*)Wl)[2 * f];
    float4 w1 = ((const float4*)Wl)[2 * f + 1];
    float d = 0.f;
    d += fmaxf(di * (a0 + bfl(hs.x)) + b0.x, 0.f) * w0.x;
    d += fmaxf(di * (a1 + bfh(hs.x)) + b0.y, 0.f) * w0.y;
    d += fmaxf(di * (a2 + bfl(hs.y)) + b0.z, 0.f) * w0.z;
    d += fmaxf(di * (a3 + bfh(hs.y)) + b0.w, 0.f) * w0.w;
    d += fmaxf(di * (a4 + bfl(hs.z)) + b1.x, 0.f) * w1.x;
    d += fmaxf(di * (a5 + bfh(hs.z)) + b1.y, 0.f) * w1.y;
    d += fmaxf(di * (a6 + bfl(hs.w)) + b1.z, 0.f) * w1.z;
    d += fmaxf(di * (a7 + bfh(hs.w)) + b1.w, 0.f) * w1.w;
    // reduce across the 8 feature lanes of this node group (masks 1,2,4)
#pragma unroll
    for (int m = 1; m <= 4; m <<= 1) d += __shfl_xor(d, m);
    if (valid && f == 0) pdot[node] = d;
}

// ---------------- final: per-graph mean of pdot + bias ----------------
__global__ __launch_bounds__(64) void final_out(const float* __restrict__ pdot,
                                                const int* __restrict__ batch,
                                                const float* __restrict__ bl,
                                                float* __restrict__ out) {
    int g = blockIdx.x;
    __shared__ int slo, shi;
    int lane = threadIdx.x;
    if (lane == 0) {
        int a = 0, b = N_NODES;
        while (a < b) { int m = (a + b) >> 1; if (batch[m] < g) a = m + 1; else b = m; }
        slo = a;
        b = N_NODES;
        while (a < b) { int m = (a + b) >> 1; if (batch[m] < g + 1) a = m + 1; else b = m; }
        shi = a;
    }
    __syncthreads();
    int lo = slo, hi = shi;
    float acc = 0.f;
    for (int i = lo + lane; i < hi; i += 64) acc += pdot[i];
#pragma unroll
    for (int off = 32; off > 0; off >>= 1) acc += __shfl_down(acc, off);
    if (lane == 0) {
        float cnt = (float)(hi - lo);
        out[g] = acc / fmaxf(cnt, 1.0f) + bl[0];
    }
}

extern "C" void kernel_launch(void* const* d_in, const int* in_sizes, int n_in,
                              void* d_out, int out_size, void* d_ws, size_t ws_size,
                              hipStream_t stream) {
    const float* x     = (const float*)d_in[0];
    const int*   src   = (const int*)d_in[1];
    const int*   dst   = (const int*)d_in[2];
    const int*   batch = (const int*)d_in[3];
    const float* W1 = (const float*)d_in[4];  const float* b1 = (const float*)d_in[5];
    const float* W2 = (const float*)d_in[6];  const float* b2 = (const float*)d_in[7];
    const float* W3 = (const float*)d_in[8];  const float* b3 = (const float*)d_in[9];
    const float* Wl = (const float*)d_in[10]; const float* bl = (const float*)d_in[11];
    float* out = (float*)d_out;

    char* ws = (char*)d_ws;
    unsigned short* Abf = (unsigned short*)ws;                       // N*F bf16 (Hn)
    unsigned short* Bbf = Abf + (size_t)N_NODES * F;                 // N*F bf16 (H)
    float* dinv    = (float*)(Bbf + (size_t)N_NODES * F);            // N
    float* pdot    = dinv + N_NODES;                                 // N
    int*   rbeg    = (int*)(pdot + N_NODES);                         // N
    int*   rend    = rbeg + N_NODES;                                 // N
    int*   bcur    = rend + N_NODES;                                 // NBUCK
    unsigned int* bpair = (unsigned int*)(bcur + NBUCK);             // NBUCK*CAP
    int*   eidx    = (int*)(bpair + (size_t)NBUCK * CAP);            // NBUCK*CAP

    const int GEMM_GRID   = (N_NODES + 127) / 128;                   // 391
    const int GATHER_GRID = (N_NODES + 31) / 32;                     // 1563 (8 nodes/wave, 4 waves/block)

    // ---- preprocessing: padded-CSR build (rbeg/rend, eidx, dinv) ----
    hipMemsetAsync(bcur, 0, NBUCK * sizeof(int), stream);
    partition_edges<<<P3_GRID, 256, 0, stream>>>(src, dst, bcur, bpair);
    bucket_sort<<<NBUCK, 256, 0, stream>>>(bpair, bcur, eidx, rbeg, rend, dinv);

    // ---- layer 1 (f32 input) ----
    gemm64_t<false><<<GEMM_GRID, 256, 0, stream>>>((const void*)x, W1, dinv, Abf, N_NODES);
    gather_layer<<<GATHER_GRID, 256, 0, stream>>>(rbeg, rend, eidx, dinv, Abf, b1, Bbf, N_NODES);

    // ---- layer 2 (bf16 input) ----
    gemm64_t<true><<<GEMM_GRID, 256, 0, stream>>>((const void*)Bbf, W2, dinv, Abf, N_NODES);
    gather_layer<<<GATHER_GRID, 256, 0, stream>>>(rbeg, rend, eidx, dinv, Abf, b2, Bbf, N_NODES);

    // ---- layer 3 (bf16 input), gather fused with pooling dot ----
    gemm64_t<true><<<GEMM_GRID, 256, 0, stream>>>((const void*)Bbf, W3, dinv, Abf, N_NODES);
    gather_pool<<<GATHER_GRID, 256, 0, stream>>>(rbeg, rend, eidx, dinv, Abf, b3, Wl, pdot, N_NODES);

    // ---- final: per-graph mean + bias ----
    final_out<<<N_GRAPHS, 64, 0, stream>>>(pdot, batch, bl, out);
}